// Round 7
// baseline (325.504 us; speedup 1.0000x reference)
//
#include <hip/hip_runtime.h>

#define LN_EPS 1e-5f

// Kernel 1: w_rowsum[p][c] = sum_k weights[p][c][k].  One wave per (p,c) row
// of 256 floats; float4 loads are fully coalesced (1 KB per wave).
__global__ __launch_bounds__(256) void wrowsum_kernel(
    const float* __restrict__ w, float* __restrict__ wr, int n_rows) {
  const int lane = threadIdx.x & 63;
  const int wv   = threadIdx.x >> 6;
  const int rc   = blockIdx.x * 4 + wv;          // p*C + c
  if (rc >= n_rows) return;
  const float4 v = reinterpret_cast<const float4*>(w)[(size_t)rc * 64 + lane];
  float s = v.x + v.y + v.z + v.w;
#pragma unroll
  for (int off = 32; off; off >>= 1) s += __shfl_xor(s, off);
  if (lane == 0) wr[rc] = s;
}

// Kernel 2: fused pointwise + LayerNorm + residual/ReLU + [C x 5] GEMV.
// 16 lanes per row (4 rows per wave, 16 rows per 256-thread block):
// each lane owns 16 channels (4x float4), so all reductions are 4-level
// __shfl_xor butterflies within 16-lane groups, serving 4 rows at once.
// DS ops per row: 7 (vs 42 in the wave-per-row version).
__global__ __launch_bounds__(256) void fused_main(
    const float* __restrict__ features,
    const float* __restrict__ wrow,
    const float* __restrict__ bias,
    const float* __restrict__ gamma,
    const float* __restrict__ beta,
    const float* __restrict__ lin_w,
    const float* __restrict__ lin_b,
    float* __restrict__ out,
    int n_rows, int P) {
  const int lane = threadIdx.x & 63;
  const int wv   = threadIdx.x >> 6;
  const int sub  = lane & 15;                    // lane within row-group
  const int rg   = lane >> 4;                    // row within wave
  const int r    = blockIdx.x * 16 + wv * 4 + rg;
  if (r >= n_rows) return;
  const int p = r % P;

  const float4* __restrict__ f4  = reinterpret_cast<const float4*>(features);
  const float4* __restrict__ w4  = reinterpret_cast<const float4*>(wrow);
  const float4* __restrict__ b4  = reinterpret_cast<const float4*>(bias);
  const float4* __restrict__ g4  = reinterpret_cast<const float4*>(gamma);
  const float4* __restrict__ t4  = reinterpret_cast<const float4*>(beta);
  const float4* __restrict__ l4  = reinterpret_cast<const float4*>(lin_w);

  // Load instruction i covers float4 idx i*16+sub: 256 B contiguous per
  // 16-lane group -> 4x 256 B segments per wave instruction (fully used).
  float4 f[4], wr[4], bs[4], g[4], bt[4];
#pragma unroll
  for (int i = 0; i < 4; ++i) {
    const int c4 = i * 16 + sub;                 // float4 index in [0,64)
    f[i]  = f4[(size_t)r * 64 + c4];
    wr[i] = w4[(size_t)p * 64 + c4];
    bs[i] = b4[(size_t)p * 64 + c4];
    g[i]  = g4[c4];
    bt[i] = t4[c4];
  }

  // point_wise = f * w_rowsum + bias; accumulate sum & sum-of-squares
  float4 pw[4];
  float s1 = 0.0f, s2 = 0.0f;
#pragma unroll
  for (int i = 0; i < 4; ++i) {
    pw[i].x = fmaf(f[i].x, wr[i].x, bs[i].x);
    pw[i].y = fmaf(f[i].y, wr[i].y, bs[i].y);
    pw[i].z = fmaf(f[i].z, wr[i].z, bs[i].z);
    pw[i].w = fmaf(f[i].w, wr[i].w, bs[i].w);
    s1 += (pw[i].x + pw[i].y) + (pw[i].z + pw[i].w);
    s2 = fmaf(pw[i].x, pw[i].x, s2);
    s2 = fmaf(pw[i].y, pw[i].y, s2);
    s2 = fmaf(pw[i].z, pw[i].z, s2);
    s2 = fmaf(pw[i].w, pw[i].w, s2);
  }
  // 4-level butterfly within the 16-lane group (xor<16 stays in group)
#pragma unroll
  for (int off = 8; off; off >>= 1) {
    s1 += __shfl_xor(s1, off);
    s2 += __shfl_xor(s2, off);
  }
  const float mu  = s1 * (1.0f / 256.0f);
  const float var = fmaf(-mu, mu, s2 * (1.0f / 256.0f));
  const float inv = rsqrtf(var + LN_EPS);

  // h = relu(f + ((pw - mu) * inv) * gamma + beta)
  float4 h[4];
#pragma unroll
  for (int i = 0; i < 4; ++i) {
    h[i].x = fmaxf(fmaf((pw[i].x - mu) * inv, g[i].x, bt[i].x) + f[i].x, 0.0f);
    h[i].y = fmaxf(fmaf((pw[i].y - mu) * inv, g[i].y, bt[i].y) + f[i].y, 0.0f);
    h[i].z = fmaxf(fmaf((pw[i].z - mu) * inv, g[i].z, bt[i].z) + f[i].z, 0.0f);
    h[i].w = fmaxf(fmaf((pw[i].w - mu) * inv, g[i].w, bt[i].w) + f[i].w, 0.0f);
  }

  // out[r][d] = sum_c h[c] * lin_w[d][c] + lin_b[d]   (lin_w L1-resident)
  float acc[5];
#pragma unroll
  for (int d = 0; d < 5; ++d) {
    float a = 0.0f;
#pragma unroll
    for (int i = 0; i < 4; ++i) {
      const float4 lw = l4[d * 64 + i * 16 + sub];
      a = fmaf(h[i].x, lw.x, a);
      a = fmaf(h[i].y, lw.y, a);
      a = fmaf(h[i].z, lw.z, a);
      a = fmaf(h[i].w, lw.w, a);
    }
    acc[d] = a;
  }
#pragma unroll
  for (int off = 8; off; off >>= 1) {
#pragma unroll
    for (int d = 0; d < 5; ++d) acc[d] += __shfl_xor(acc[d], off);
  }

  if (sub < 5) {
    float v;
    switch (sub) {                               // static acc index (no scratch)
      case 0:  v = acc[0]; break;
      case 1:  v = acc[1]; break;
      case 2:  v = acc[2]; break;
      case 3:  v = acc[3]; break;
      default: v = acc[4]; break;
    }
    out[(size_t)r * 5 + sub] = v + lin_b[sub];
  }
}

extern "C" void kernel_launch(void* const* d_in, const int* in_sizes, int n_in,
                              void* d_out, int out_size, void* d_ws, size_t ws_size,
                              hipStream_t stream) {
  const float* features = (const float*)d_in[0];  // [B,P,C]
  const float* weights  = (const float*)d_in[1];  // [P,C,C]
  const float* bias     = (const float*)d_in[2];  // [P,C]
  const float* gamma    = (const float*)d_in[3];  // [C]
  const float* beta     = (const float*)d_in[4];  // [C]
  const float* lin_w    = (const float*)d_in[5];  // [D,C]
  const float* lin_b    = (const float*)d_in[6];  // [D]
  float* out = (float*)d_out;

  const int C  = 256;
  const int PC = in_sizes[2];          // P*C
  const int P  = PC / C;               // 25
  const int BP = in_sizes[0] / C;      // B*P rows = 204800

  float* wr = (float*)d_ws;            // [P*C] workspace

  // Kernel 1: row-sums of weights (6.55 MB read, ~2 us)
  wrowsum_kernel<<<(PC + 3) / 4, 256, 0, stream>>>(weights, wr, PC);

  // Kernel 2: fused main pass (one sweep over features, 16 rows/block)
  fused_main<<<(BP + 15) / 16, 256, 0, stream>>>(
      features, wr, bias, gamma, beta, lin_w, lin_b, out, BP, P);
}

// Round 9
// 315.325 us; speedup vs baseline: 1.0323x; 1.0323x over previous
//
#include <hip/hip_runtime.h>

#define LN_EPS 1e-5f

// Kernel 1: w_rowsum[p][c] = sum_k weights[p][c][k].  One wave per (p,c) row.
__global__ __launch_bounds__(256) void wrowsum_kernel(
    const float* __restrict__ w, float* __restrict__ wr, int n_rows) {
  const int lane = threadIdx.x & 63;
  const int wv   = threadIdx.x >> 6;
  const int rc   = blockIdx.x * 4 + wv;          // p*C + c
  if (rc >= n_rows) return;
  const float4 v = reinterpret_cast<const float4*>(w)[(size_t)rc * 64 + lane];
  float s = v.x + v.y + v.z + v.w;
#pragma unroll
  for (int off = 32; off; off >>= 1) s += __shfl_xor(s, off);
  if (lane == 0) wr[rc] = s;
}

// Kernel 2: fused pointwise + LayerNorm + residual/ReLU + [C x 5] GEMV.
// Block = (p, chunk of 64 b-rows). All row-invariant operands (wrow, bias,
// gamma, beta, lin_w -> ~144 VGPRs) are hoisted out of the row loop, so the
// marginal per-row traffic is ONLY the 1 KB features payload (register
// double-buffered prefetch). 16 lanes per row; 4 rows/wave; 4 iters/group.
__global__ __launch_bounds__(256, 2) void fused_main(
    const float* __restrict__ features,
    const float* __restrict__ wrow,
    const float* __restrict__ bias,
    const float* __restrict__ gamma,
    const float* __restrict__ beta,
    const float* __restrict__ lin_w,
    const float* __restrict__ lin_b,
    float* __restrict__ out,
    int B, int P) {
  const int lane = threadIdx.x & 63;
  const int wv   = threadIdx.x >> 6;
  const int sub  = lane & 15;                    // lane within 16-lane row group
  const int grp  = wv * 4 + (lane >> 4);         // group id in block [0,16)
  const int p    = blockIdx.y;

  const float4* __restrict__ f4 = reinterpret_cast<const float4*>(features);
  const float4* __restrict__ w4 = reinterpret_cast<const float4*>(wrow);
  const float4* __restrict__ b4 = reinterpret_cast<const float4*>(bias);
  const float4* __restrict__ g4 = reinterpret_cast<const float4*>(gamma);
  const float4* __restrict__ t4 = reinterpret_cast<const float4*>(beta);
  const float4* __restrict__ l4 = reinterpret_cast<const float4*>(lin_w);

  // ---- hoisted row-invariant operands (live in registers across the loop)
  float4 wr[4], bs[4], g[4], bt[4], lw[5][4];
#pragma unroll
  for (int i = 0; i < 4; ++i) {
    const int c4 = i * 16 + sub;
    wr[i] = w4[(size_t)p * 64 + c4];
    bs[i] = b4[(size_t)p * 64 + c4];
    g[i]  = g4[c4];
    bt[i] = t4[c4];
  }
#pragma unroll
  for (int d = 0; d < 5; ++d)
#pragma unroll
    for (int i = 0; i < 4; ++i) lw[d][i] = l4[d * 64 + i * 16 + sub];
  const float lb = (sub < 5) ? lin_b[sub] : 0.0f;

  // ---- row loop: b = chunk*64 + grp + 16*it, it = 0..3
  int b = blockIdx.x * 64 + grp;
  const size_t fstep = (size_t)16 * P * 64;      // float4 stride per iteration
  const size_t ostep = (size_t)16 * P * 5;
  const float4* fp = f4 + ((size_t)b * P + p) * 64 + sub;
  size_t orow = ((size_t)b * P + p) * 5;

  float4 fc[4], fn[4];
  bool ok = (b < B);
  if (ok) {
#pragma unroll
    for (int i = 0; i < 4; ++i) fc[i] = fp[i * 16];
  }
  fp += fstep;

  for (int it = 0; it < 4; ++it) {
    // prefetch next row's features (hides HBM latency under compute)
    const bool okn = (b + 16 * (it + 1) < B) && (it < 3);
    if (okn) {
#pragma unroll
      for (int i = 0; i < 4; ++i) fn[i] = fp[i * 16];
    }
    fp += fstep;

    if (ok) {
      // point_wise = f * w_rowsum + bias; LN stats
      float4 pw[4];
      float s1 = 0.0f, s2 = 0.0f;
#pragma unroll
      for (int i = 0; i < 4; ++i) {
        pw[i].x = fmaf(fc[i].x, wr[i].x, bs[i].x);
        pw[i].y = fmaf(fc[i].y, wr[i].y, bs[i].y);
        pw[i].z = fmaf(fc[i].z, wr[i].z, bs[i].z);
        pw[i].w = fmaf(fc[i].w, wr[i].w, bs[i].w);
        s1 += (pw[i].x + pw[i].y) + (pw[i].z + pw[i].w);
        s2 = fmaf(pw[i].x, pw[i].x, s2);
        s2 = fmaf(pw[i].y, pw[i].y, s2);
        s2 = fmaf(pw[i].z, pw[i].z, s2);
        s2 = fmaf(pw[i].w, pw[i].w, s2);
      }
#pragma unroll
      for (int off = 8; off; off >>= 1) {
        s1 += __shfl_xor(s1, off);
        s2 += __shfl_xor(s2, off);
      }
      const float mu  = s1 * (1.0f / 256.0f);
      const float var = fmaf(-mu, mu, s2 * (1.0f / 256.0f));
      const float inv = rsqrtf(var + LN_EPS);

      // h = relu(f + norm(pw)*gamma + beta); acc[d] += h . lin_w[d]
      float acc[5] = {0.0f, 0.0f, 0.0f, 0.0f, 0.0f};
#pragma unroll
      for (int i = 0; i < 4; ++i) {
        float4 h;
        h.x = fmaxf(fmaf((pw[i].x - mu) * inv, g[i].x, bt[i].x) + fc[i].x, 0.0f);
        h.y = fmaxf(fmaf((pw[i].y - mu) * inv, g[i].y, bt[i].y) + fc[i].y, 0.0f);
        h.z = fmaxf(fmaf((pw[i].z - mu) * inv, g[i].z, bt[i].z) + fc[i].z, 0.0f);
        h.w = fmaxf(fmaf((pw[i].w - mu) * inv, g[i].w, bt[i].w) + fc[i].w, 0.0f);
#pragma unroll
        for (int d = 0; d < 5; ++d) {
          acc[d] = fmaf(h.x, lw[d][i].x, acc[d]);
          acc[d] = fmaf(h.y, lw[d][i].y, acc[d]);
          acc[d] = fmaf(h.z, lw[d][i].z, acc[d]);
          acc[d] = fmaf(h.w, lw[d][i].w, acc[d]);
        }
      }
#pragma unroll
      for (int off = 8; off; off >>= 1) {
#pragma unroll
        for (int d = 0; d < 5; ++d) acc[d] += __shfl_xor(acc[d], off);
      }

      if (sub < 5) {
        float v;
        switch (sub) {                           // static index (no scratch)
          case 0:  v = acc[0]; break;
          case 1:  v = acc[1]; break;
          case 2:  v = acc[2]; break;
          case 3:  v = acc[3]; break;
          default: v = acc[4]; break;
        }
        out[orow + sub] = v + lb;
      }
    }

    // rotate prefetch buffer
#pragma unroll
    for (int i = 0; i < 4; ++i) fc[i] = fn[i];
    ok = okn;
    orow += ostep;
  }
}

extern "C" void kernel_launch(void* const* d_in, const int* in_sizes, int n_in,
                              void* d_out, int out_size, void* d_ws, size_t ws_size,
                              hipStream_t stream) {
  const float* features = (const float*)d_in[0];  // [B,P,C]
  const float* weights  = (const float*)d_in[1];  // [P,C,C]
  const float* bias     = (const float*)d_in[2];  // [P,C]
  const float* gamma    = (const float*)d_in[3];  // [C]
  const float* beta     = (const float*)d_in[4];  // [C]
  const float* lin_w    = (const float*)d_in[5];  // [D,C]
  const float* lin_b    = (const float*)d_in[6];  // [D]
  float* out = (float*)d_out;

  const int C  = 256;
  const int PC = in_sizes[2];          // P*C
  const int P  = PC / C;               // 25
  const int BP = in_sizes[0] / C;      // B*P rows
  const int B  = BP / P;               // 8192

  float* wr = (float*)d_ws;            // [P*C] workspace

  // Kernel 1: row-sums of weights (6.55 MB read, ~3 us)
  wrowsum_kernel<<<(PC + 3) / 4, 256, 0, stream>>>(weights, wr, PC);

  // Kernel 2: fused main pass. Grid: x = b-chunks of 64, y = p.
  const int chunks = (B + 63) / 64;
  fused_main<<<dim3(chunks, P), 256, 0, stream>>>(
      features, wr, bias, gamma, beta, lin_w, lin_b, out, B, P);
}

// Round 11
// 310.329 us; speedup vs baseline: 1.0489x; 1.0161x over previous
//
#include <hip/hip_runtime.h>

#define LN_EPS 1e-5f

// Kernel 1: w_rowsum[p][c] = sum_k weights[p][c][k].  One wave per (p,c) row.
__global__ __launch_bounds__(256) void wrowsum_kernel(
    const float* __restrict__ w, float* __restrict__ wr, int n_rows) {
  const int lane = threadIdx.x & 63;
  const int wv   = threadIdx.x >> 6;
  const int rc   = blockIdx.x * 4 + wv;          // p*C + c
  if (rc >= n_rows) return;
  const float4 v = reinterpret_cast<const float4*>(w)[(size_t)rc * 64 + lane];
  float s = v.x + v.y + v.z + v.w;
#pragma unroll
  for (int off = 32; off; off >>= 1) s += __shfl_xor(s, off);
  if (lane == 0) wr[rc] = s;
}

// DPP rotate-add within the 16-lane row (VALU pipe, zero DS traffic).
#define DPP_ADD(s, ctrl)                                                     \
  ((s) + __int_as_float(__builtin_amdgcn_update_dpp(                         \
             0, __float_as_int(s), (ctrl), 0xF, 0xF, true)))

__device__ __forceinline__ float red32(float s) {
  s = DPP_ADD(s, 0x128);  // row_ror:8
  s = DPP_ADD(s, 0x124);  // row_ror:4
  s = DPP_ADD(s, 0x122);  // row_ror:2
  s = DPP_ADD(s, 0x121);  // row_ror:1  -> all 16 lanes of the row hold row-sum
  // cross-16 within the 32-lane group: ds_swizzle xor-16 (1 DS op)
  s += __int_as_float(__builtin_amdgcn_ds_swizzle(__float_as_int(s), 0x401F));
  return s;
}

// Kernel 2: fused pointwise + LayerNorm + residual/ReLU + [C x 5] GEMV.
// 32 lanes per row (2 groups/wave), 2x float4 per lane. Row-invariant
// operands hoisted (~72 VGPR). Reductions: 4x DPP rotate-add + 1 ds_swizzle
// per value (no __shfl butterflies). 8 rows per group; prefetch depth 1.
__global__ __launch_bounds__(256) void fused_main(
    const float* __restrict__ features,
    const float* __restrict__ wrow,
    const float* __restrict__ bias,
    const float* __restrict__ gamma,
    const float* __restrict__ beta,
    const float* __restrict__ lin_w,
    const float* __restrict__ lin_b,
    float* __restrict__ out,
    int B, int P) {
  const int lane = threadIdx.x & 63;
  const int wv   = threadIdx.x >> 6;
  const int sub  = lane & 31;                    // lane within 32-lane row group
  const int grp  = wv * 2 + (lane >> 5);         // group id in block [0,8)
  const int p    = blockIdx.y;

  const float4* __restrict__ f4 = reinterpret_cast<const float4*>(features);
  const float4* __restrict__ w4 = reinterpret_cast<const float4*>(wrow);
  const float4* __restrict__ b4 = reinterpret_cast<const float4*>(bias);
  const float4* __restrict__ g4 = reinterpret_cast<const float4*>(gamma);
  const float4* __restrict__ t4 = reinterpret_cast<const float4*>(beta);
  const float4* __restrict__ l4 = reinterpret_cast<const float4*>(lin_w);

  // ---- hoisted row-invariant operands (c4 = i*32 + sub, i in {0,1})
  float4 wr[2], bs[2], g[2], bt[2], lw[5][2];
#pragma unroll
  for (int i = 0; i < 2; ++i) {
    const int c4 = i * 32 + sub;
    wr[i] = w4[(size_t)p * 64 + c4];
    bs[i] = b4[(size_t)p * 64 + c4];
    g[i]  = g4[c4];
    bt[i] = t4[c4];
  }
#pragma unroll
  for (int d = 0; d < 5; ++d)
#pragma unroll
    for (int i = 0; i < 2; ++i) lw[d][i] = l4[d * 64 + i * 32 + sub];
  const float lb = (sub < 5) ? lin_b[sub] : 0.0f;

  // ---- row loop: b = chunk*64 + it*8 + grp, it = 0..7
  const int b0 = blockIdx.x * 64 + grp;
  const float4* fp = f4 + ((size_t)b0 * P + p) * 64 + sub;
  const size_t fstep = (size_t)8 * P * 64;       // float4 stride per iteration
  size_t orow = ((size_t)b0 * P + p) * 5;
  const size_t ostep = (size_t)8 * P * 5;

  float4 fc[2], fn[2];
  bool ok = (b0 < B);
  if (ok) { fc[0] = fp[0]; fc[1] = fp[32]; }
  fp += fstep;

  for (int it = 0; it < 8; ++it) {
    const bool okn = (it < 7) && (b0 + 8 * (it + 1) < B);
    if (okn) { fn[0] = fp[0]; fn[1] = fp[32]; }
    fp += fstep;

    if (ok) {
      // point_wise = f * w_rowsum + bias; LN stats
      float4 pw[2];
      float s1 = 0.0f, s2 = 0.0f;
#pragma unroll
      for (int i = 0; i < 2; ++i) {
        pw[i].x = fmaf(fc[i].x, wr[i].x, bs[i].x);
        pw[i].y = fmaf(fc[i].y, wr[i].y, bs[i].y);
        pw[i].z = fmaf(fc[i].z, wr[i].z, bs[i].z);
        pw[i].w = fmaf(fc[i].w, wr[i].w, bs[i].w);
        s1 += (pw[i].x + pw[i].y) + (pw[i].z + pw[i].w);
        s2 = fmaf(pw[i].x, pw[i].x, s2);
        s2 = fmaf(pw[i].y, pw[i].y, s2);
        s2 = fmaf(pw[i].z, pw[i].z, s2);
        s2 = fmaf(pw[i].w, pw[i].w, s2);
      }
      s1 = red32(s1);
      s2 = red32(s2);
      const float mu  = s1 * (1.0f / 256.0f);
      const float var = fmaf(-mu, mu, s2 * (1.0f / 256.0f));
      const float inv = rsqrtf(var + LN_EPS);

      // h = relu(f + norm(pw)*gamma + beta); acc[d] += h . lin_w[d]
      float acc0 = 0.f, acc1 = 0.f, acc2 = 0.f, acc3 = 0.f, acc4 = 0.f;
#pragma unroll
      for (int i = 0; i < 2; ++i) {
        float4 h;
        h.x = fmaxf(fmaf((pw[i].x - mu) * inv, g[i].x, bt[i].x) + fc[i].x, 0.0f);
        h.y = fmaxf(fmaf((pw[i].y - mu) * inv, g[i].y, bt[i].y) + fc[i].y, 0.0f);
        h.z = fmaxf(fmaf((pw[i].z - mu) * inv, g[i].z, bt[i].z) + fc[i].z, 0.0f);
        h.w = fmaxf(fmaf((pw[i].w - mu) * inv, g[i].w, bt[i].w) + fc[i].w, 0.0f);
        acc0 = fmaf(h.x, lw[0][i].x, acc0); acc0 = fmaf(h.y, lw[0][i].y, acc0);
        acc0 = fmaf(h.z, lw[0][i].z, acc0); acc0 = fmaf(h.w, lw[0][i].w, acc0);
        acc1 = fmaf(h.x, lw[1][i].x, acc1); acc1 = fmaf(h.y, lw[1][i].y, acc1);
        acc1 = fmaf(h.z, lw[1][i].z, acc1); acc1 = fmaf(h.w, lw[1][i].w, acc1);
        acc2 = fmaf(h.x, lw[2][i].x, acc2); acc2 = fmaf(h.y, lw[2][i].y, acc2);
        acc2 = fmaf(h.z, lw[2][i].z, acc2); acc2 = fmaf(h.w, lw[2][i].w, acc2);
        acc3 = fmaf(h.x, lw[3][i].x, acc3); acc3 = fmaf(h.y, lw[3][i].y, acc3);
        acc3 = fmaf(h.z, lw[3][i].z, acc3); acc3 = fmaf(h.w, lw[3][i].w, acc3);
        acc4 = fmaf(h.x, lw[4][i].x, acc4); acc4 = fmaf(h.y, lw[4][i].y, acc4);
        acc4 = fmaf(h.z, lw[4][i].z, acc4); acc4 = fmaf(h.w, lw[4][i].w, acc4);
      }
      acc0 = red32(acc0);
      acc1 = red32(acc1);
      acc2 = red32(acc2);
      acc3 = red32(acc3);
      acc4 = red32(acc4);

      if (sub < 5) {
        float v;
        switch (sub) {                           // static index (no scratch)
          case 0:  v = acc0; break;
          case 1:  v = acc1; break;
          case 2:  v = acc2; break;
          case 3:  v = acc3; break;
          default: v = acc4; break;
        }
        out[orow + sub] = v + lb;
      }
    }

    fc[0] = fn[0]; fc[1] = fn[1];
    ok = okn;
    orow += ostep;
  }
}

extern "C" void kernel_launch(void* const* d_in, const int* in_sizes, int n_in,
                              void* d_out, int out_size, void* d_ws, size_t ws_size,
                              hipStream_t stream) {
  const float* features = (const float*)d_in[0];  // [B,P,C]
  const float* weights  = (const float*)d_in[1];  // [P,C,C]
  const float* bias     = (const float*)d_in[2];  // [P,C]
  const float* gamma    = (const float*)d_in[3];  // [C]
  const float* beta     = (const float*)d_in[4];  // [C]
  const float* lin_w    = (const float*)d_in[5];  // [D,C]
  const float* lin_b    = (const float*)d_in[6];  // [D]
  float* out = (float*)d_out;

  const int C  = 256;
  const int PC = in_sizes[2];          // P*C
  const int P  = PC / C;               // 25
  const int BP = in_sizes[0] / C;      // B*P rows
  const int B  = BP / P;               // 8192

  float* wr = (float*)d_ws;            // [P*C] workspace

  // Kernel 1: row-sums of weights (6.55 MB read, ~3 us)
  wrowsum_kernel<<<(PC + 3) / 4, 256, 0, stream>>>(weights, wr, PC);

  // Kernel 2: fused main pass. Grid: x = b-chunks of 64, y = p.
  const int chunks = (B + 63) / 64;
  fused_main<<<dim3(chunks, P), 256, 0, stream>>>(
      features, wr, bias, gamma, beta, lin_w, lin_b, out, B, P);
}